// Round 5
// baseline (324.024 us; speedup 1.0000x reference)
//
#include <hip/hip_runtime.h>

#define NN 100000
#define SE 16
#define BB 4096
#define CAP 64            // in-degree bucket capacity; in-deg ~ Poisson(16), P(>64) negligible
#define NTILE 1563        // ceil(NN / 64)
#define NBUCKET 1024      // bucket-role blocks in fused kernel
#define NMM 782           // mm-role blocks (782*2 tiles >= 1563)

typedef float        vf4 __attribute__((ext_vector_type(4)));
typedef unsigned int vu2 __attribute__((ext_vector_type(2)));

__device__ __forceinline__ float leaky(float x) { return x > 0.0f ? x : 0.2f * x; }

__device__ __forceinline__ unsigned f2bf(float f) {     // RNE f32 -> bf16 (low 16)
    unsigned u = __float_as_uint(f);
    u += 0x7fffu + ((u >> 16) & 1u);
    return u >> 16;
}
__device__ __forceinline__ float bf2f(unsigned short h) {
    return __uint_as_float(((unsigned)h) << 16);
}
__device__ __forceinline__ float4 ldh(const ushort4* __restrict__ hb, size_t idx) {
    ushort4 v = hb[idx];
    float4 r;
    r.x = bf2f(v.x); r.y = bf2f(v.y); r.z = bf2f(v.z); r.w = bf2f(v.w);
    return r;
}

#define FMA4(a, sx, wv) \
    a.x = fmaf(sx, wv.x, a.x); a.y = fmaf(sx, wv.y, a.y); \
    a.z = fmaf(sx, wv.z, a.z); a.w = fmaf(sx, wv.w, a.w);

// ---------------- fused: bucket build (XCD-partitioned, NT reads) + h=X@W ----------------
// blocks 0..1023: bucket role. grp = blockIdx&7 -> one XCD per dst range under
//   round-robin mapping; NT edge loads keep the 3.2 MB dirty esrc slice L2-resident.
// blocks 1024..1805: mm role. 64-row tiles, W staged once, NT X loads / NT hb stores.
__global__ __launch_bounds__(256) void k_bm(const float4* __restrict__ X4,
                                            const float4* __restrict__ W4,
                                            const float* __restrict__ att,
                                            const int* __restrict__ edges,
                                            int* __restrict__ cnt,
                                            int* __restrict__ esrc,
                                            ushort4* __restrict__ hb,
                                            float* __restrict__ s,
                                            float* __restrict__ t) {
    __shared__ float4 Wl[64][16];    // Wl[k][q] = W[k][4q..4q+3]
    __shared__ float4 xr[64][16];    // 64 staged rows
    const int tid = threadIdx.x;

    if (blockIdx.x < NBUCKET) {
        const int grp   = blockIdx.x & 7;
        const int chunk = blockIdx.x >> 3;
        const int lo = grp * 12500, hi = lo + 12500;
        const int e0 = chunk * 12500, e1 = e0 + 12500;
        for (int e = e0 + tid; e < e1; e += 256) {
            int j = __builtin_nontemporal_load(&edges[e]);
            if (j >= lo && j < hi) {
                int i = e >> 4;
                if (j != i) {
                    int p = atomicAdd(&cnt[j], 1);
                    if (p < CAP) esrc[j * CAP + p] = i;
                }
            }
        }
        return;
    }

    // ---- mm role ----
    const int lane = tid & 63;
    const int q    = lane & 15;
    const int slot = ((tid >> 6) << 2) | (lane >> 4);   // 0..15

    for (int idx = tid; idx < 1024; idx += 256) {
        vf4 v = __builtin_nontemporal_load((const vf4*)W4 + idx);
        Wl[idx >> 4][idx & 15] = make_float4(v.x, v.y, v.z, v.w);
    }
    const float4 ai = ((const float4*)att)[q];
    const float4 aj = ((const float4*)att)[16 + q];

    for (int tile = blockIdx.x - NBUCKET; tile < NTILE; tile += NMM) {
        const int r0 = tile * 64;
        __syncthreads();
#pragma unroll
        for (int u = 0; u < 4; ++u) {
            int idx = u * 256 + tid;
            int row = r0 + (idx >> 4);
            if (row < NN) {
                vf4 v = __builtin_nontemporal_load((const vf4*)X4 + (size_t)row * 16 + (idx & 15));
                xr[idx >> 4][idx & 15] = make_float4(v.x, v.y, v.z, v.w);
            }
        }
        __syncthreads();

        const int rbase = slot * 4;
        float4 acc0 = {0,0,0,0}, acc1 = {0,0,0,0}, acc2 = {0,0,0,0}, acc3 = {0,0,0,0};
#pragma unroll
        for (int k4 = 0; k4 < 16; ++k4) {
            float4 w0 = Wl[k4 * 4 + 0][q];
            float4 w1 = Wl[k4 * 4 + 1][q];
            float4 w2 = Wl[k4 * 4 + 2][q];
            float4 w3 = Wl[k4 * 4 + 3][q];
            float4 x0 = xr[rbase + 0][k4];
            float4 x1 = xr[rbase + 1][k4];
            float4 x2 = xr[rbase + 2][k4];
            float4 x3 = xr[rbase + 3][k4];
            FMA4(acc0, x0.x, w0) FMA4(acc0, x0.y, w1) FMA4(acc0, x0.z, w2) FMA4(acc0, x0.w, w3)
            FMA4(acc1, x1.x, w0) FMA4(acc1, x1.y, w1) FMA4(acc1, x1.z, w2) FMA4(acc1, x1.w, w3)
            FMA4(acc2, x2.x, w0) FMA4(acc2, x2.y, w1) FMA4(acc2, x2.z, w2) FMA4(acc2, x2.w, w3)
            FMA4(acc3, x3.x, w0) FMA4(acc3, x3.y, w1) FMA4(acc3, x3.z, w2) FMA4(acc3, x3.w, w3)
        }

        float4 accs[4] = {acc0, acc1, acc2, acc3};
#pragma unroll
        for (int rr = 0; rr < 4; ++rr) {
            int row = r0 + rbase + rr;
            if (row >= NN) continue;
            float4 a = accs[rr];
            vu2 hv;
            hv.x = f2bf(a.x) | (f2bf(a.y) << 16);
            hv.y = f2bf(a.z) | (f2bf(a.w) << 16);
            __builtin_nontemporal_store(hv, (vu2*)hb + (size_t)row * 16 + q);
            float ps = a.x * ai.x + a.y * ai.y + a.z * ai.z + a.w * ai.w;
            float pt = a.x * aj.x + a.y * aj.y + a.z * aj.z + a.w * aj.w;
#pragma unroll
            for (int off = 1; off < 16; off <<= 1) {
                ps += __shfl_xor(ps, off);
                pt += __shfl_xor(pt, off);
            }
            if (q == 0) { s[row] = ps; t[row] = pt; }
        }
    }
}

// ---------------- gather-softmax-aggregate ----------------
// 4 nodes/wave, 16 lanes x 4 dims (bf16 gathers, 128 B/edge).
// No max subtraction: |alpha| <= ~3, exp is exact-safe in f32.
__global__ __launch_bounds__(256) void k_gat(const ushort4* __restrict__ hb,
                                             const int* __restrict__ cnt,
                                             const int* __restrict__ esrc,
                                             const float* __restrict__ s,
                                             const float* __restrict__ t,
                                             const float* __restrict__ bias,
                                             float4* __restrict__ g4) {
    const int tid  = threadIdx.x;
    const int lane = tid & 63;
    const int w    = tid >> 6;
    const int q    = lane & 15;
    const int sub  = lane >> 4;
    const int j    = blockIdx.x * 16 + w * 4 + sub;   // 6250*16 = 100000 exact
    const int lsrc = sub * 16;

    const float sj = s[j];
    int deg = __builtin_nontemporal_load(&cnt[j]); if (deg > CAP) deg = CAP;
    const int base = j * CAP;

    // parallel edge phase: lane q handles edges q, q+16, q+32, q+48 of its node
    int   sc[4] = {0, 0, 0, 0};
    float ev[4] = {0.f, 0.f, 0.f, 0.f};
#pragma unroll
    for (int u = 0; u < 4; ++u) {
        int e = q + u * 16;
        if (e < deg) {
            int srcn = __builtin_nontemporal_load(&esrc[base + e]);
            sc[u] = srcn;
            ev[u] = expf(leaky(sj + t[srcn]));
        }
    }
    float den = ev[0] + ev[1] + ev[2] + ev[3];
#pragma unroll
    for (int off = 1; off < 16; off <<= 1) den += __shfl_xor(den, off);

    // self loop
    float evs = expf(leaky(sj + t[j]));
    den += evs;
    float4 hj = ldh(hb, (size_t)j * 16 + q);
    float4 acc;
    acc.x = evs * hj.x; acc.y = evs * hj.y; acc.z = evs * hj.z; acc.w = evs * hj.w;

    // serial accumulate: 4 independent chains per wave, loads batched 4-deep
#pragma unroll
    for (int u = 0; u < 4; ++u) {
        if (!__any(deg > u * 16)) break;
#pragma unroll
        for (int kk = 0; kk < 16; kk += 4) {
            int e0 = u * 16 + kk;
            if (!__any(deg > e0)) break;
            int   sA = __shfl(sc[u], lsrc + kk + 0);
            int   sB = __shfl(sc[u], lsrc + kk + 1);
            int   sC = __shfl(sc[u], lsrc + kk + 2);
            int   sD = __shfl(sc[u], lsrc + kk + 3);
            float eA = __shfl(ev[u], lsrc + kk + 0);
            float eB = __shfl(ev[u], lsrc + kk + 1);
            float eC = __shfl(ev[u], lsrc + kk + 2);
            float eD = __shfl(ev[u], lsrc + kk + 3);
            float4 vA = {0,0,0,0}, vB = {0,0,0,0}, vC = {0,0,0,0}, vD = {0,0,0,0};
            if (e0 + 0 < deg) vA = ldh(hb, (size_t)sA * 16 + q);
            if (e0 + 1 < deg) vB = ldh(hb, (size_t)sB * 16 + q);
            if (e0 + 2 < deg) vC = ldh(hb, (size_t)sC * 16 + q);
            if (e0 + 3 < deg) vD = ldh(hb, (size_t)sD * 16 + q);
            FMA4(acc, eA, vA) FMA4(acc, eB, vB) FMA4(acc, eC, vC) FMA4(acc, eD, vD)
        }
    }

    float4 bv = ((const float4*)bias)[q];
    float inv = 1.0f / (den + 1e-16f);
    float4 v;
    v.x = acc.x * inv + bv.x; v.y = acc.y * inv + bv.y;
    v.z = acc.z * inv + bv.z; v.w = acc.w * inv + bv.w;
    float sq = v.x * v.x + v.y * v.y + v.z * v.z + v.w * v.w;
#pragma unroll
    for (int off = 1; off < 16; off <<= 1) sq += __shfl_xor(sq, off);
    float nm = fmaxf(sqrtf(sq), 1e-12f);
    float4 o;
    o.x = v.x / nm; o.y = v.y / nm; o.z = v.z / nm; o.w = v.w / nm;
    g4[(size_t)j * 16 + q] = o;
}

// ---------------- scores + reg loss ----------------
__global__ __launch_bounds__(256) void k5_score(const float4* __restrict__ X4,
                                                const float4* __restrict__ g4,
                                                const int* __restrict__ user,
                                                const int* __restrict__ pos,
                                                const int* __restrict__ neg,
                                                const int* __restrict__ posr,
                                                const int* __restrict__ negr,
                                                float* __restrict__ out) {
    const int tid  = threadIdx.x;
    const int lane = tid & 63;
    const int q    = lane & 15;
    const int sub  = lane >> 4;
    const int b    = blockIdx.x * 16 + (tid >> 6) * 4 + sub;

    int u = user[b], p = pos[b], n = neg[b], pr = posr[b], nr = negr[b];
    float4 xu = X4[(size_t)u * 16 + q],  gu = g4[(size_t)u * 16 + q];
    float4 xp = X4[(size_t)p * 16 + q],  gp = g4[(size_t)p * 16 + q];
    float4 xn = X4[(size_t)n * 16 + q],  gn = g4[(size_t)n * 16 + q];
    float4 xq = X4[(size_t)pr * 16 + q], gq = g4[(size_t)pr * 16 + q];
    float4 xm = X4[(size_t)nr * 16 + q], gm = g4[(size_t)nr * 16 + q];

#define DOT(a, c) (a.x * c.x + a.y * c.y + a.z * c.z + a.w * c.w)
    float dp = DOT(xu, xp) + DOT(gu, gp);
    float dn = DOT(xu, xn) + DOT(gu, gn);
    float dq = DOT(xu, xq) + DOT(gu, gq);
    float dm = DOT(xu, xm) + DOT(gu, gm);
    float rg = 0.5f    * (DOT(xu, xu) + DOT(gu, gu) + DOT(xp, xp) + DOT(gp, gp)
                        + DOT(xn, xn) + DOT(gn, gn))
             + 0.0005f * (DOT(xq, xq) + DOT(gq, gq) + DOT(xm, xm) + DOT(gm, gm));
#undef DOT
#pragma unroll
    for (int off = 1; off < 16; off <<= 1) {
        dp += __shfl_xor(dp, off);
        dn += __shfl_xor(dn, off);
        dq += __shfl_xor(dq, off);
        dm += __shfl_xor(dm, off);
    }
    if (q == 0) {
        out[b]      = dp + 0.1f * dq;
        out[BB + b] = dn + 0.1f * dm;
    }
#pragma unroll
    for (int off = 16; off < 64; off <<= 1) rg += __shfl_xor(rg, off);
#pragma unroll
    for (int off = 1; off < 16; off <<= 1) rg += __shfl_xor(rg, off);
    if (lane == 0) unsafeAtomicAdd(&out[2 * BB], rg);
}

extern "C" void kernel_launch(void* const* d_in, const int* in_sizes, int n_in,
                              void* d_out, int out_size, void* d_ws, size_t ws_size,
                              hipStream_t stream) {
    const float* X    = (const float*)d_in[0];
    const float* W    = (const float*)d_in[1];
    const float* att  = (const float*)d_in[2];
    const float* bias = (const float*)d_in[3];
    const int* edges  = (const int*)d_in[4];
    const int* user   = (const int*)d_in[5];
    const int* pos    = (const int*)d_in[6];
    const int* neg    = (const int*)d_in[7];
    const int* posr   = (const int*)d_in[8];
    const int* negr   = (const int*)d_in[9];
    float* out = (float*)d_out;

    ushort4* hb  = (ushort4*)d_ws;                     // NN*16 ushort4 (bf16 h)
    float4*  g4  = (float4*)(hb + (size_t)NN * 16);    // NN*16 float4
    float*   s   = (float*)(g4 + (size_t)NN * 16);     // NN
    float*   t   = s + NN;                             // NN
    int*     cnt = (int*)(t + NN);                     // NN
    int*     esrc = cnt + NN;                          // NN*CAP

    hipMemsetAsync(cnt, 0, (size_t)NN * sizeof(int), stream);
    hipMemsetAsync(out, 0, (size_t)(2 * BB + 1) * sizeof(float), stream);

    k_bm<<<NBUCKET + NMM, 256, 0, stream>>>((const float4*)X, (const float4*)W, att,
                                            edges, cnt, esrc, hb, s, t);
    k_gat<<<6250, 256, 0, stream>>>(hb, cnt, esrc, s, t, bias, g4);
    k5_score<<<256, 256, 0, stream>>>((const float4*)X, g4, user, pos, neg, posr, negr, out);
}

// Round 6
// 216.939 us; speedup vs baseline: 1.4936x; 1.4936x over previous
//
#include <hip/hip_runtime.h>

#define NN 100000
#define SE 16
#define BB 4096
#define CAP 64            // in-degree bucket capacity; in-deg ~ Poisson(16), P(>64) negligible
#define NTILE 1563        // ceil(NN / 64)

__device__ __forceinline__ float leaky(float x) { return x > 0.0f ? x : 0.2f * x; }

__device__ __forceinline__ unsigned short f2bf(float f) {     // RNE f32 -> bf16
    unsigned u = __float_as_uint(f);
    u += 0x7fffu + ((u >> 16) & 1u);
    return (unsigned short)(u >> 16);
}
__device__ __forceinline__ float bf2f(unsigned short h) {
    return __uint_as_float(((unsigned)h) << 16);
}
__device__ __forceinline__ float4 ldh(const ushort4* __restrict__ hb, size_t idx) {
    ushort4 v = hb[idx];
    float4 r;
    r.x = bf2f(v.x); r.y = bf2f(v.y); r.z = bf2f(v.z); r.w = bf2f(v.w);
    return r;
}

#define FMA4(a, sx, wv) \
    a.x = fmaf(sx, wv.x, a.x); a.y = fmaf(sx, wv.y, a.y); \
    a.z = fmaf(sx, wv.z, a.z); a.w = fmaf(sx, wv.w, a.w);

// ---------------- bucket build, XCD-partitioned, NT edge stream ----------------
// grid 1024: group = blockIdx&7 (one XCD per group under round-robin mapping),
// chunk = blockIdx>>3. Each group keeps only dsts in its 12500-node range, so its
// scattered esrc writes live in a 3.2 MB slice of its own L2. NT loads keep the
// 6.4 MB edge stream from evicting the dirty slice (round-4 counters showed 71 MB
// writeback churn = stream-eviction of partially-filled lines).
__global__ __launch_bounds__(256) void k_bucket(const int* __restrict__ edges,
                                                int* __restrict__ cnt,
                                                int* __restrict__ esrc) {
    const int grp   = blockIdx.x & 7;
    const int chunk = blockIdx.x >> 3;
    const int lo = grp * 12500, hi = lo + 12500;
    const int e0 = chunk * 12500, e1 = e0 + 12500;
    for (int e = e0 + threadIdx.x; e < e1; e += 256) {
        int j = __builtin_nontemporal_load(&edges[e]);
        if (j >= lo && j < hi) {
            int i = e >> 4;
            if (j != i) {
                int p = atomicAdd(&cnt[j], 1);
                if (p < CAP) esrc[j * CAP + p] = i;
            }
        }
    }
}

// ---------------- h = X@W (bf16 out) + s,t ----------------
// 64-row tiles; 16 lane-slots x 4 rows each; lane q owns cols 4q..4q+3.
__global__ __launch_bounds__(256) void k_mm(const float4* __restrict__ X4,
                                            const float4* __restrict__ W4,
                                            const float* __restrict__ att,
                                            ushort4* __restrict__ hb,
                                            float* __restrict__ s,
                                            float* __restrict__ t) {
    __shared__ float4 Wl[64][16];    // Wl[k][q] = W[k][4q..4q+3]
    __shared__ float4 xr[64][16];    // 64 staged rows
    const int tid  = threadIdx.x;
    const int lane = tid & 63;
    const int q    = lane & 15;
    const int slot = ((tid >> 6) << 2) | (lane >> 4);   // 0..15

    for (int idx = tid; idx < 1024; idx += 256)
        Wl[idx >> 4][idx & 15] = W4[idx];
    const float4 ai = ((const float4*)att)[q];
    const float4 aj = ((const float4*)att)[16 + q];

    for (int tile = blockIdx.x; tile < NTILE; tile += gridDim.x) {
        const int r0 = tile * 64;
        __syncthreads();
#pragma unroll
        for (int u = 0; u < 4; ++u) {
            int idx = u * 256 + tid;
            int row = r0 + (idx >> 4);
            if (row < NN) xr[idx >> 4][idx & 15] = X4[(size_t)row * 16 + (idx & 15)];
        }
        __syncthreads();

        const int rbase = slot * 4;
        float4 acc0 = {0,0,0,0}, acc1 = {0,0,0,0}, acc2 = {0,0,0,0}, acc3 = {0,0,0,0};
#pragma unroll
        for (int k4 = 0; k4 < 16; ++k4) {
            float4 w0 = Wl[k4 * 4 + 0][q];
            float4 w1 = Wl[k4 * 4 + 1][q];
            float4 w2 = Wl[k4 * 4 + 2][q];
            float4 w3 = Wl[k4 * 4 + 3][q];
            float4 x0 = xr[rbase + 0][k4];
            float4 x1 = xr[rbase + 1][k4];
            float4 x2 = xr[rbase + 2][k4];
            float4 x3 = xr[rbase + 3][k4];
            FMA4(acc0, x0.x, w0) FMA4(acc0, x0.y, w1) FMA4(acc0, x0.z, w2) FMA4(acc0, x0.w, w3)
            FMA4(acc1, x1.x, w0) FMA4(acc1, x1.y, w1) FMA4(acc1, x1.z, w2) FMA4(acc1, x1.w, w3)
            FMA4(acc2, x2.x, w0) FMA4(acc2, x2.y, w1) FMA4(acc2, x2.z, w2) FMA4(acc2, x2.w, w3)
            FMA4(acc3, x3.x, w0) FMA4(acc3, x3.y, w1) FMA4(acc3, x3.z, w2) FMA4(acc3, x3.w, w3)
        }

        float4 accs[4] = {acc0, acc1, acc2, acc3};
#pragma unroll
        for (int rr = 0; rr < 4; ++rr) {
            int row = r0 + rbase + rr;
            if (row >= NN) continue;
            float4 a = accs[rr];
            ushort4 hv;
            hv.x = f2bf(a.x); hv.y = f2bf(a.y); hv.z = f2bf(a.z); hv.w = f2bf(a.w);
            hb[(size_t)row * 16 + q] = hv;
            float ps = a.x * ai.x + a.y * ai.y + a.z * ai.z + a.w * ai.w;
            float pt = a.x * aj.x + a.y * aj.y + a.z * aj.z + a.w * aj.w;
#pragma unroll
            for (int off = 1; off < 16; off <<= 1) {
                ps += __shfl_xor(ps, off);
                pt += __shfl_xor(pt, off);
            }
            if (q == 0) { s[row] = ps; t[row] = pt; }
        }
    }
}

// ---------------- gather-softmax-aggregate ----------------
// 4 nodes/wave, 16 lanes x 4 dims (bf16 gathers, 128 B/edge).
// No max subtraction: |alpha| <= ~3, exp is exact-safe in f32.
__global__ __launch_bounds__(256) void k_gat(const ushort4* __restrict__ hb,
                                             const int* __restrict__ cnt,
                                             const int* __restrict__ esrc,
                                             const float* __restrict__ s,
                                             const float* __restrict__ t,
                                             const float* __restrict__ bias,
                                             float4* __restrict__ g4) {
    const int tid  = threadIdx.x;
    const int lane = tid & 63;
    const int w    = tid >> 6;
    const int q    = lane & 15;
    const int sub  = lane >> 4;
    const int j    = blockIdx.x * 16 + w * 4 + sub;   // 6250*16 = 100000 exact
    const int lsrc = sub * 16;

    const float sj = s[j];
    int deg = __builtin_nontemporal_load(&cnt[j]); if (deg > CAP) deg = CAP;
    const int base = j * CAP;

    // parallel edge phase: lane q handles edges q, q+16, q+32, q+48 of its node
    int   sc[4] = {0, 0, 0, 0};
    float ev[4] = {0.f, 0.f, 0.f, 0.f};
#pragma unroll
    for (int u = 0; u < 4; ++u) {
        int e = q + u * 16;
        if (e < deg) {
            int srcn = __builtin_nontemporal_load(&esrc[base + e]);
            sc[u] = srcn;
            ev[u] = expf(leaky(sj + t[srcn]));
        }
    }
    float den = ev[0] + ev[1] + ev[2] + ev[3];
#pragma unroll
    for (int off = 1; off < 16; off <<= 1) den += __shfl_xor(den, off);

    // self loop
    float evs = expf(leaky(sj + t[j]));
    den += evs;
    float4 hj = ldh(hb, (size_t)j * 16 + q);
    float4 acc;
    acc.x = evs * hj.x; acc.y = evs * hj.y; acc.z = evs * hj.z; acc.w = evs * hj.w;

    // serial accumulate: 4 independent chains per wave, loads batched 4-deep
#pragma unroll
    for (int u = 0; u < 4; ++u) {
        if (!__any(deg > u * 16)) break;
#pragma unroll
        for (int kk = 0; kk < 16; kk += 4) {
            int e0 = u * 16 + kk;
            if (!__any(deg > e0)) break;
            int   sA = __shfl(sc[u], lsrc + kk + 0);
            int   sB = __shfl(sc[u], lsrc + kk + 1);
            int   sC = __shfl(sc[u], lsrc + kk + 2);
            int   sD = __shfl(sc[u], lsrc + kk + 3);
            float eA = __shfl(ev[u], lsrc + kk + 0);
            float eB = __shfl(ev[u], lsrc + kk + 1);
            float eC = __shfl(ev[u], lsrc + kk + 2);
            float eD = __shfl(ev[u], lsrc + kk + 3);
            float4 vA = {0,0,0,0}, vB = {0,0,0,0}, vC = {0,0,0,0}, vD = {0,0,0,0};
            if (e0 + 0 < deg) vA = ldh(hb, (size_t)sA * 16 + q);
            if (e0 + 1 < deg) vB = ldh(hb, (size_t)sB * 16 + q);
            if (e0 + 2 < deg) vC = ldh(hb, (size_t)sC * 16 + q);
            if (e0 + 3 < deg) vD = ldh(hb, (size_t)sD * 16 + q);
            FMA4(acc, eA, vA) FMA4(acc, eB, vB) FMA4(acc, eC, vC) FMA4(acc, eD, vD)
        }
    }

    float4 bv = ((const float4*)bias)[q];
    float inv = 1.0f / (den + 1e-16f);
    float4 v;
    v.x = acc.x * inv + bv.x; v.y = acc.y * inv + bv.y;
    v.z = acc.z * inv + bv.z; v.w = acc.w * inv + bv.w;
    float sq = v.x * v.x + v.y * v.y + v.z * v.z + v.w * v.w;
#pragma unroll
    for (int off = 1; off < 16; off <<= 1) sq += __shfl_xor(sq, off);
    float nm = fmaxf(sqrtf(sq), 1e-12f);
    float4 o;
    o.x = v.x / nm; o.y = v.y / nm; o.z = v.z / nm; o.w = v.w / nm;
    g4[(size_t)j * 16 + q] = o;
}

// ---------------- scores + reg loss ----------------
__global__ __launch_bounds__(256) void k5_score(const float4* __restrict__ X4,
                                                const float4* __restrict__ g4,
                                                const int* __restrict__ user,
                                                const int* __restrict__ pos,
                                                const int* __restrict__ neg,
                                                const int* __restrict__ posr,
                                                const int* __restrict__ negr,
                                                float* __restrict__ out) {
    const int tid  = threadIdx.x;
    const int lane = tid & 63;
    const int q    = lane & 15;
    const int sub  = lane >> 4;
    const int b    = blockIdx.x * 16 + (tid >> 6) * 4 + sub;

    int u = user[b], p = pos[b], n = neg[b], pr = posr[b], nr = negr[b];
    float4 xu = X4[(size_t)u * 16 + q],  gu = g4[(size_t)u * 16 + q];
    float4 xp = X4[(size_t)p * 16 + q],  gp = g4[(size_t)p * 16 + q];
    float4 xn = X4[(size_t)n * 16 + q],  gn = g4[(size_t)n * 16 + q];
    float4 xq = X4[(size_t)pr * 16 + q], gq = g4[(size_t)pr * 16 + q];
    float4 xm = X4[(size_t)nr * 16 + q], gm = g4[(size_t)nr * 16 + q];

#define DOT(a, c) (a.x * c.x + a.y * c.y + a.z * c.z + a.w * c.w)
    float dp = DOT(xu, xp) + DOT(gu, gp);
    float dn = DOT(xu, xn) + DOT(gu, gn);
    float dq = DOT(xu, xq) + DOT(gu, gq);
    float dm = DOT(xu, xm) + DOT(gu, gm);
    float rg = 0.5f    * (DOT(xu, xu) + DOT(gu, gu) + DOT(xp, xp) + DOT(gp, gp)
                        + DOT(xn, xn) + DOT(gn, gn))
             + 0.0005f * (DOT(xq, xq) + DOT(gq, gq) + DOT(xm, xm) + DOT(gm, gm));
#undef DOT
#pragma unroll
    for (int off = 1; off < 16; off <<= 1) {
        dp += __shfl_xor(dp, off);
        dn += __shfl_xor(dn, off);
        dq += __shfl_xor(dq, off);
        dm += __shfl_xor(dm, off);
    }
    if (q == 0) {
        out[b]      = dp + 0.1f * dq;
        out[BB + b] = dn + 0.1f * dm;
    }
#pragma unroll
    for (int off = 16; off < 64; off <<= 1) rg += __shfl_xor(rg, off);
#pragma unroll
    for (int off = 1; off < 16; off <<= 1) rg += __shfl_xor(rg, off);
    if (lane == 0) unsafeAtomicAdd(&out[2 * BB], rg);
}

extern "C" void kernel_launch(void* const* d_in, const int* in_sizes, int n_in,
                              void* d_out, int out_size, void* d_ws, size_t ws_size,
                              hipStream_t stream) {
    const float* X    = (const float*)d_in[0];
    const float* W    = (const float*)d_in[1];
    const float* att  = (const float*)d_in[2];
    const float* bias = (const float*)d_in[3];
    const int* edges  = (const int*)d_in[4];
    const int* user   = (const int*)d_in[5];
    const int* pos    = (const int*)d_in[6];
    const int* neg    = (const int*)d_in[7];
    const int* posr   = (const int*)d_in[8];
    const int* negr   = (const int*)d_in[9];
    float* out = (float*)d_out;

    ushort4* hb  = (ushort4*)d_ws;                     // NN*16 ushort4 (bf16 h)
    float4*  g4  = (float4*)(hb + (size_t)NN * 16);    // NN*16 float4
    float*   s   = (float*)(g4 + (size_t)NN * 16);     // NN
    float*   t   = s + NN;                             // NN
    int*     cnt = (int*)(t + NN);                     // NN
    int*     esrc = cnt + NN;                          // NN*CAP

    hipMemsetAsync(cnt, 0, (size_t)NN * sizeof(int), stream);
    hipMemsetAsync(out, 0, (size_t)(2 * BB + 1) * sizeof(float), stream);

    k_bucket<<<1024, 256, 0, stream>>>(edges, cnt, esrc);
    k_mm<<<782, 256, 0, stream>>>((const float4*)X, (const float4*)W, att, hb, s, t);
    k_gat<<<6250, 256, 0, stream>>>(hb, cnt, esrc, s, t, bias, g4);
    k5_score<<<256, 256, 0, stream>>>((const float4*)X, g4, user, pos, neg, posr, negr, out);
}

// Round 7
// 185.095 us; speedup vs baseline: 1.7506x; 1.1720x over previous
//
#include <hip/hip_runtime.h>

#define NN 100000
#define SE 16
#define NE 1600000        // NN*SE
#define BB 4096
#define CAP 64            // per-node bucket capacity (deg ~ Poisson(16))
#define NTILE 1563        // ceil(NN / 64)
#define NBIN 250          // fine bins of 400 nodes: 250*400 = 100000 exactly
#define BINW 400
#define SEGCAP 12288      // per-bin segment capacity (avg 6400 + align waste ~3000)
#define NP1 391           // ceil(NE / 4096)

__device__ __forceinline__ float leaky(float x) { return x > 0.0f ? x : 0.2f * x; }

__device__ __forceinline__ unsigned short f2bf(float f) {     // RNE f32 -> bf16
    unsigned u = __float_as_uint(f);
    u += 0x7fffu + ((u >> 16) & 1u);
    return (unsigned short)(u >> 16);
}
__device__ __forceinline__ float bf2f(unsigned short h) {
    return __uint_as_float(((unsigned)h) << 16);
}
__device__ __forceinline__ float4 ldh(const ushort4* __restrict__ hb, size_t idx) {
    ushort4 v = hb[idx];
    float4 r;
    r.x = bf2f(v.x); r.y = bf2f(v.y); r.z = bf2f(v.z); r.w = bf2f(v.w);
    return r;
}

#define FMA4(a, sx, wv) \
    a.x = fmaf(sx, wv.x, a.x); a.y = fmaf(sx, wv.y, a.y); \
    a.z = fmaf(sx, wv.z, a.z); a.w = fmaf(sx, wv.w, a.w);

// ---------------- pass 1: bin edges by dst into 250 segments ----------------
// Each block: 4096 edges. LDS histogram -> line-aligned (x16) global reservation
// per bin -> scatter packed (jloc<<17)|src to per-bin hot fronts. All reserved
// ranges are 64B-line-aligned => every pairs line has exactly one writer block
// (no cross-XCD dirty-line hazard), and lines fill completely before eviction.
__global__ __launch_bounds__(256) void k_bin(const int* __restrict__ edges,
                                             int* __restrict__ cursor,
                                             unsigned* __restrict__ pairs) {
    __shared__ int hist[NBIN];
    __shared__ int gbase[NBIN];
    __shared__ int resv[NBIN];
    __shared__ int off[NBIN];
    const int tid = threadIdx.x;
    const int e0  = blockIdx.x * 4096;

    if (tid < NBIN) hist[tid] = 0;
    __syncthreads();

    int pb[16];   // packed pair
    int bn[16];   // bin (-1 = invalid)
#pragma unroll
    for (int it = 0; it < 16; ++it) {
        int e = e0 + it * 256 + tid;
        int b = -1, pr = 0;
        if (e < NE) {
            int j = __builtin_nontemporal_load(&edges[e]);
            int i = e >> 4;
            if (j != i) {
                b  = j / BINW;
                pr = ((j - b * BINW) << 17) | i;
            }
        }
        bn[it] = b; pb[it] = pr;
        if (b >= 0) atomicAdd(&hist[b], 1);
    }
    __syncthreads();

    if (tid < NBIN) {
        int c   = hist[tid];
        int res = (c + 15) & ~15;          // line-aligned reservation
        int gb  = res ? atomicAdd(&cursor[tid], res) : 0;
        if (gb + res > SEGCAP) gb = SEGCAP;   // overflow guard (statistically never)
        gbase[tid] = gb; resv[tid] = res; off[tid] = 0;
    }
    __syncthreads();

#pragma unroll
    for (int it = 0; it < 16; ++it) {
        int b = bn[it];
        if (b >= 0) {
            int o   = atomicAdd(&off[b], 1);
            int pos = gbase[b] + o;
            if (pos < SEGCAP) pairs[(size_t)b * SEGCAP + pos] = (unsigned)pb[it];
        }
    }
    __syncthreads();

    if (tid < NBIN) {                      // sentinel-fill alignment gap
        int base = gbase[tid];
        for (int k = hist[tid]; k < resv[tid]; ++k) {
            int pos = base + k;
            if (pos < SEGCAP) pairs[(size_t)tid * SEGCAP + pos] = 0xFFFFFFFFu;
        }
    }
}

// ---------------- pass 2: segment -> per-node buckets ----------------
// One block per (bin, jloc-quarter). Quarters are 16-node-aligned so every
// cnt line and every esrc bucket line has exactly one writer block. Counters
// live in LDS -> zero global atomics; cnt written wholesale (no memset needed).
__global__ __launch_bounds__(256) void k_scat(const unsigned* __restrict__ pairs,
                                              const int* __restrict__ cursor,
                                              int* __restrict__ cnt,
                                              int* __restrict__ esrc) {
    __shared__ int lcnt[112];
    const int bin = blockIdx.x >> 2;
    const int sub = blockIdx.x & 3;
    const int jl0 = sub * 112;
    const int jl1 = (jl0 + 112 < BINW) ? jl0 + 112 : BINW;   // sub3: 336..400
    const int nloc = jl1 - jl0;
    if (threadIdx.x < nloc) lcnt[threadIdx.x] = 0;
    __syncthreads();

    int n = cursor[bin]; if (n > SEGCAP) n = SEGCAP;
    const unsigned* seg = pairs + (size_t)bin * SEGCAP;
    for (int k = threadIdx.x; k < n; k += 256) {
        unsigned pr = seg[k];
        if ((int)pr < 0) continue;         // sentinel
        int jl = (int)(pr >> 17);
        if (jl < jl0 || jl >= jl1) continue;
        int i = (int)(pr & 0x1FFFFu);
        int p = atomicAdd(&lcnt[jl - jl0], 1);
        if (p < CAP) esrc[((size_t)(bin * BINW + jl)) * CAP + p] = i;
    }
    __syncthreads();
    if (threadIdx.x < nloc) cnt[bin * BINW + jl0 + threadIdx.x] = lcnt[threadIdx.x];
}

// ---------------- h = X@W (bf16 out) + s,t ----------------
__global__ __launch_bounds__(256) void k_mm(const float4* __restrict__ X4,
                                            const float4* __restrict__ W4,
                                            const float* __restrict__ att,
                                            ushort4* __restrict__ hb,
                                            float* __restrict__ s,
                                            float* __restrict__ t) {
    __shared__ float4 Wl[64][16];    // Wl[k][q] = W[k][4q..4q+3]
    __shared__ float4 xr[64][16];    // 64 staged rows
    const int tid  = threadIdx.x;
    const int lane = tid & 63;
    const int q    = lane & 15;
    const int slot = ((tid >> 6) << 2) | (lane >> 4);   // 0..15

    for (int idx = tid; idx < 1024; idx += 256)
        Wl[idx >> 4][idx & 15] = W4[idx];
    const float4 ai = ((const float4*)att)[q];
    const float4 aj = ((const float4*)att)[16 + q];

    for (int tile = blockIdx.x; tile < NTILE; tile += gridDim.x) {
        const int r0 = tile * 64;
        __syncthreads();
#pragma unroll
        for (int u = 0; u < 4; ++u) {
            int idx = u * 256 + tid;
            int row = r0 + (idx >> 4);
            if (row < NN) xr[idx >> 4][idx & 15] = X4[(size_t)row * 16 + (idx & 15)];
        }
        __syncthreads();

        const int rbase = slot * 4;
        float4 acc0 = {0,0,0,0}, acc1 = {0,0,0,0}, acc2 = {0,0,0,0}, acc3 = {0,0,0,0};
#pragma unroll
        for (int k4 = 0; k4 < 16; ++k4) {
            float4 w0 = Wl[k4 * 4 + 0][q];
            float4 w1 = Wl[k4 * 4 + 1][q];
            float4 w2 = Wl[k4 * 4 + 2][q];
            float4 w3 = Wl[k4 * 4 + 3][q];
            float4 x0 = xr[rbase + 0][k4];
            float4 x1 = xr[rbase + 1][k4];
            float4 x2 = xr[rbase + 2][k4];
            float4 x3 = xr[rbase + 3][k4];
            FMA4(acc0, x0.x, w0) FMA4(acc0, x0.y, w1) FMA4(acc0, x0.z, w2) FMA4(acc0, x0.w, w3)
            FMA4(acc1, x1.x, w0) FMA4(acc1, x1.y, w1) FMA4(acc1, x1.z, w2) FMA4(acc1, x1.w, w3)
            FMA4(acc2, x2.x, w0) FMA4(acc2, x2.y, w1) FMA4(acc2, x2.z, w2) FMA4(acc2, x2.w, w3)
            FMA4(acc3, x3.x, w0) FMA4(acc3, x3.y, w1) FMA4(acc3, x3.z, w2) FMA4(acc3, x3.w, w3)
        }

        float4 accs[4] = {acc0, acc1, acc2, acc3};
#pragma unroll
        for (int rr = 0; rr < 4; ++rr) {
            int row = r0 + rbase + rr;
            if (row >= NN) continue;
            float4 a = accs[rr];
            ushort4 hv;
            hv.x = f2bf(a.x); hv.y = f2bf(a.y); hv.z = f2bf(a.z); hv.w = f2bf(a.w);
            hb[(size_t)row * 16 + q] = hv;
            float ps = a.x * ai.x + a.y * ai.y + a.z * ai.z + a.w * ai.w;
            float pt = a.x * aj.x + a.y * aj.y + a.z * aj.z + a.w * aj.w;
#pragma unroll
            for (int off = 1; off < 16; off <<= 1) {
                ps += __shfl_xor(ps, off);
                pt += __shfl_xor(pt, off);
            }
            if (q == 0) { s[row] = ps; t[row] = pt; }
        }
    }
}

// ---------------- gather-softmax-aggregate ----------------
// 4 nodes/wave, 16 lanes x 4 dims (bf16 gathers, 128 B/edge).
// No max subtraction: |alpha| <= ~3, exp is exact-safe in f32.
__global__ __launch_bounds__(256) void k_gat(const ushort4* __restrict__ hb,
                                             const int* __restrict__ cnt,
                                             const int* __restrict__ esrc,
                                             const float* __restrict__ s,
                                             const float* __restrict__ t,
                                             const float* __restrict__ bias,
                                             float4* __restrict__ g4) {
    const int tid  = threadIdx.x;
    const int lane = tid & 63;
    const int w    = tid >> 6;
    const int q    = lane & 15;
    const int sub  = lane >> 4;
    const int j    = blockIdx.x * 16 + w * 4 + sub;   // 6250*16 = 100000 exact
    const int lsrc = sub * 16;

    const float sj = s[j];
    int deg = __builtin_nontemporal_load(&cnt[j]); if (deg > CAP) deg = CAP;
    const int base = j * CAP;

    // parallel edge phase: lane q handles edges q, q+16, q+32, q+48 of its node
    int   sc[4] = {0, 0, 0, 0};
    float ev[4] = {0.f, 0.f, 0.f, 0.f};
#pragma unroll
    for (int u = 0; u < 4; ++u) {
        int e = q + u * 16;
        if (e < deg) {
            int srcn = __builtin_nontemporal_load(&esrc[base + e]);
            sc[u] = srcn;
            ev[u] = expf(leaky(sj + t[srcn]));
        }
    }
    float den = ev[0] + ev[1] + ev[2] + ev[3];
#pragma unroll
    for (int off = 1; off < 16; off <<= 1) den += __shfl_xor(den, off);

    // self loop
    float evs = expf(leaky(sj + t[j]));
    den += evs;
    float4 hj = ldh(hb, (size_t)j * 16 + q);
    float4 acc;
    acc.x = evs * hj.x; acc.y = evs * hj.y; acc.z = evs * hj.z; acc.w = evs * hj.w;

    // serial accumulate: 4 independent chains per wave, loads batched 4-deep
#pragma unroll
    for (int u = 0; u < 4; ++u) {
        if (!__any(deg > u * 16)) break;
#pragma unroll
        for (int kk = 0; kk < 16; kk += 4) {
            int e0 = u * 16 + kk;
            if (!__any(deg > e0)) break;
            int   sA = __shfl(sc[u], lsrc + kk + 0);
            int   sB = __shfl(sc[u], lsrc + kk + 1);
            int   sC = __shfl(sc[u], lsrc + kk + 2);
            int   sD = __shfl(sc[u], lsrc + kk + 3);
            float eA = __shfl(ev[u], lsrc + kk + 0);
            float eB = __shfl(ev[u], lsrc + kk + 1);
            float eC = __shfl(ev[u], lsrc + kk + 2);
            float eD = __shfl(ev[u], lsrc + kk + 3);
            float4 vA = {0,0,0,0}, vB = {0,0,0,0}, vC = {0,0,0,0}, vD = {0,0,0,0};
            if (e0 + 0 < deg) vA = ldh(hb, (size_t)sA * 16 + q);
            if (e0 + 1 < deg) vB = ldh(hb, (size_t)sB * 16 + q);
            if (e0 + 2 < deg) vC = ldh(hb, (size_t)sC * 16 + q);
            if (e0 + 3 < deg) vD = ldh(hb, (size_t)sD * 16 + q);
            FMA4(acc, eA, vA) FMA4(acc, eB, vB) FMA4(acc, eC, vC) FMA4(acc, eD, vD)
        }
    }

    float4 bv = ((const float4*)bias)[q];
    float inv = 1.0f / (den + 1e-16f);
    float4 v;
    v.x = acc.x * inv + bv.x; v.y = acc.y * inv + bv.y;
    v.z = acc.z * inv + bv.z; v.w = acc.w * inv + bv.w;
    float sq = v.x * v.x + v.y * v.y + v.z * v.z + v.w * v.w;
#pragma unroll
    for (int off = 1; off < 16; off <<= 1) sq += __shfl_xor(sq, off);
    float nm = fmaxf(sqrtf(sq), 1e-12f);
    float4 o;
    o.x = v.x / nm; o.y = v.y / nm; o.z = v.z / nm; o.w = v.w / nm;
    g4[(size_t)j * 16 + q] = o;
}

// ---------------- scores + reg loss ----------------
__global__ __launch_bounds__(256) void k5_score(const float4* __restrict__ X4,
                                                const float4* __restrict__ g4,
                                                const int* __restrict__ user,
                                                const int* __restrict__ pos,
                                                const int* __restrict__ neg,
                                                const int* __restrict__ posr,
                                                const int* __restrict__ negr,
                                                float* __restrict__ out) {
    const int tid  = threadIdx.x;
    const int lane = tid & 63;
    const int q    = lane & 15;
    const int sub  = lane >> 4;
    const int b    = blockIdx.x * 16 + (tid >> 6) * 4 + sub;

    int u = user[b], p = pos[b], n = neg[b], pr = posr[b], nr = negr[b];
    float4 xu = X4[(size_t)u * 16 + q],  gu = g4[(size_t)u * 16 + q];
    float4 xp = X4[(size_t)p * 16 + q],  gp = g4[(size_t)p * 16 + q];
    float4 xn = X4[(size_t)n * 16 + q],  gn = g4[(size_t)n * 16 + q];
    float4 xq = X4[(size_t)pr * 16 + q], gq = g4[(size_t)pr * 16 + q];
    float4 xm = X4[(size_t)nr * 16 + q], gm = g4[(size_t)nr * 16 + q];

#define DOT(a, c) (a.x * c.x + a.y * c.y + a.z * c.z + a.w * c.w)
    float dp = DOT(xu, xp) + DOT(gu, gp);
    float dn = DOT(xu, xn) + DOT(gu, gn);
    float dq = DOT(xu, xq) + DOT(gu, gq);
    float dm = DOT(xu, xm) + DOT(gu, gm);
    float rg = 0.5f    * (DOT(xu, xu) + DOT(gu, gu) + DOT(xp, xp) + DOT(gp, gp)
                        + DOT(xn, xn) + DOT(gn, gn))
             + 0.0005f * (DOT(xq, xq) + DOT(gq, gq) + DOT(xm, xm) + DOT(gm, gm));
#undef DOT
#pragma unroll
    for (int off = 1; off < 16; off <<= 1) {
        dp += __shfl_xor(dp, off);
        dn += __shfl_xor(dn, off);
        dq += __shfl_xor(dq, off);
        dm += __shfl_xor(dm, off);
    }
    if (q == 0) {
        out[b]      = dp + 0.1f * dq;
        out[BB + b] = dn + 0.1f * dm;
    }
#pragma unroll
    for (int off = 16; off < 64; off <<= 1) rg += __shfl_xor(rg, off);
#pragma unroll
    for (int off = 1; off < 16; off <<= 1) rg += __shfl_xor(rg, off);
    if (lane == 0) unsafeAtomicAdd(&out[2 * BB], rg);
}

extern "C" void kernel_launch(void* const* d_in, const int* in_sizes, int n_in,
                              void* d_out, int out_size, void* d_ws, size_t ws_size,
                              hipStream_t stream) {
    const float* X    = (const float*)d_in[0];
    const float* W    = (const float*)d_in[1];
    const float* att  = (const float*)d_in[2];
    const float* bias = (const float*)d_in[3];
    const int* edges  = (const int*)d_in[4];
    const int* user   = (const int*)d_in[5];
    const int* pos    = (const int*)d_in[6];
    const int* neg    = (const int*)d_in[7];
    const int* posr   = (const int*)d_in[8];
    const int* negr   = (const int*)d_in[9];
    float* out = (float*)d_out;

    ushort4*  hb     = (ushort4*)d_ws;                       // NN*16 ushort4 (bf16 h)
    float4*   g4     = (float4*)(hb + (size_t)NN * 16);      // NN*16 float4
    float*    s      = (float*)(g4 + (size_t)NN * 16);       // NN
    float*    t      = s + NN;                               // NN
    int*      cnt    = (int*)(t + NN);                       // NN
    int*      esrc   = cnt + NN;                             // NN*CAP
    unsigned* pairs  = (unsigned*)(esrc + (size_t)NN * CAP); // NBIN*SEGCAP
    int*      cursor = (int*)(pairs + (size_t)NBIN * SEGCAP);// NBIN

    hipMemsetAsync(cursor, 0, 256 * sizeof(int), stream);
    hipMemsetAsync(out, 0, (size_t)(2 * BB + 1) * sizeof(float), stream);

    k_bin<<<NP1, 256, 0, stream>>>(edges, cursor, pairs);
    k_scat<<<NBIN * 4, 256, 0, stream>>>(pairs, cursor, cnt, esrc);
    k_mm<<<782, 256, 0, stream>>>((const float4*)X, (const float4*)W, att, hb, s, t);
    k_gat<<<6250, 256, 0, stream>>>(hb, cnt, esrc, s, t, bias, g4);
    k5_score<<<256, 256, 0, stream>>>((const float4*)X, g4, user, pos, neg, posr, negr, out);
}